// Round 1
// baseline (422.264 us; speedup 1.0000x reference)
//
#include <hip/hip_runtime.h>
#include <hip/hip_bf16.h>

#define N_NODES 100000
#define N_EDGES 1000000
#define DIM 64
#define NORM_INV 0.01f
#define LN_EPS 1e-5f

typedef __attribute__((ext_vector_type(8))) short short8;
typedef __attribute__((ext_vector_type(4))) float f32x4;

__device__ __forceinline__ unsigned short f32_to_bf16_rne(float f) {
    union { float f; unsigned u; } x; x.f = f;
    unsigned r = x.u + 0x7FFFu + ((x.u >> 16) & 1u);
    return (unsigned short)(r >> 16);
}

// ---------------------------------------------------------------------------
// Kernel 1: x = h @ W_lin^T + b_lin  -> xf (f32) and xbf (bf16)
// Block = 256 threads = 4 waves; each wave computes 4 rows; lane j = output col.
// W_lin staged in LDS (padded 68 floats/row for float4 reads).
// ---------------------------------------------------------------------------
__global__ __launch_bounds__(256) void proj_kernel(
    const float* __restrict__ h, const float* __restrict__ W,
    const float* __restrict__ bl, float* __restrict__ xf,
    unsigned short* __restrict__ xbf) {
    __shared__ __align__(16) float Wl[64 * 68];
    __shared__ __align__(16) float hs[4][4 * 68];
    const int tid = threadIdx.x;
    const int lane = tid & 63;
    const int wv = tid >> 6;

    for (int i = tid; i < 4096; i += 256) {
        int r = i >> 6, c = i & 63;
        Wl[r * 68 + c] = W[i];
    }
    const int n0 = blockIdx.x * 16 + wv * 4;
#pragma unroll
    for (int r = 0; r < 4; ++r)
        hs[wv][r * 68 + lane] = h[(size_t)(n0 + r) * DIM + lane];
    __syncthreads();

    float bj = bl[lane];
    float acc[4] = {bj, bj, bj, bj};
#pragma unroll
    for (int k4 = 0; k4 < 16; ++k4) {
        f32x4 w4 = *(const f32x4*)&Wl[lane * 68 + k4 * 4];
#pragma unroll
        for (int r = 0; r < 4; ++r) {
            f32x4 h4 = *(const f32x4*)&hs[wv][r * 68 + k4 * 4];
            acc[r] = fmaf(w4[0], h4[0], acc[r]);
            acc[r] = fmaf(w4[1], h4[1], acc[r]);
            acc[r] = fmaf(w4[2], h4[2], acc[r]);
            acc[r] = fmaf(w4[3], h4[3], acc[r]);
        }
    }
#pragma unroll
    for (int r = 0; r < 4; ++r) {
        size_t o = (size_t)(n0 + r) * DIM + lane;
        xf[o] = acc[r];
        xbf[o] = f32_to_bf16_rne(acc[r]);
    }
}

// ---------------------------------------------------------------------------
// Kernel 2: per-edge attention MLP (bf16 MFMA) + attention-weighted scatter.
// One wave handles 16 edges. B = att_W1^T (K=128 part) lives in registers:
// 4 n-tiles x 4 k-steps of mfma_f32_16x16x32_bf16. A rows gathered from xbf.
// dist column (k=128) + bias folded in epilogue. att pre-scaled by 1/100.
// ---------------------------------------------------------------------------
__global__ __launch_bounds__(256) void edge_kernel(
    const int* __restrict__ edges, const float* __restrict__ dist,
    const float* __restrict__ emask, const float* __restrict__ att_W1,
    const float* __restrict__ att_b1, const float* __restrict__ att_W2,
    const float* __restrict__ att_b2, const float* __restrict__ xf,
    const unsigned short* __restrict__ xbf, float* __restrict__ agg) {
    const int lane = threadIdx.x & 63;
    const int wv = threadIdx.x >> 6;
    const int c = lane & 15;   // MFMA col / A-row-within-tile
    const int q = lane >> 4;   // quad

    // Preload B fragments (W1^T) + per-lane epilogue constants, once per block.
    short8 bfrag[4][4];
    float b1v[4], w2v[4], w1c[4];
#pragma unroll
    for (int nt = 0; nt < 4; ++nt) {
        const int j = nt * 16 + c;
        b1v[nt] = att_b1[j];
        w2v[nt] = att_W2[j];
        w1c[nt] = att_W1[j * 129 + 128];
#pragma unroll
        for (int ks = 0; ks < 4; ++ks) {
            short8 t;
#pragma unroll
            for (int jj = 0; jj < 8; ++jj)
                t[jj] = (short)f32_to_bf16_rne(att_W1[j * 129 + ks * 32 + q * 8 + jj]);
            bfrag[nt][ks] = t;
        }
    }
    const float b2 = att_b2[0];

    const int ntiles = N_EDGES / 64;  // 64 edges per block-iteration
    for (int bt = blockIdx.x; bt < ntiles; bt += gridDim.x) {
        const int e0 = bt * 64 + wv * 16;
        // lane c holds indices for edge e0+c
        const int er = edges[e0 + c];            // row
        const int ec = edges[N_EDGES + e0 + c];  // col

        // Gather A fragments: k-steps 0,1 from x[row], 2,3 from x[col].
        short8 afrag[4];
#pragma unroll
        for (int ks = 0; ks < 4; ++ks) {
            const int idx = (ks < 2) ? er : ec;
            const int koff = (ks & 1) * 32 + q * 8;
            afrag[ks] = *(const short8*)(xbf + (size_t)idx * DIM + koff);
        }

        f32x4 acc[4];
#pragma unroll
        for (int nt = 0; nt < 4; ++nt) acc[nt] = (f32x4){0.f, 0.f, 0.f, 0.f};
#pragma unroll
        for (int ks = 0; ks < 4; ++ks)
#pragma unroll
            for (int nt = 0; nt < 4; ++nt)
                acc[nt] = __builtin_amdgcn_mfma_f32_16x16x32_bf16(
                    afrag[ks], bfrag[nt][ks], acc[nt], 0, 0, 0);

        // Epilogue: +b1 + dist*W1[:,128], silu, dot with W2, sigmoid, scale.
        float att[4];
#pragma unroll
        for (int r = 0; r < 4; ++r) {
            const int e = e0 + q * 4 + r;  // edge owned by this quad/reg
            const float dr = dist[e];
            float p = 0.f;
#pragma unroll
            for (int nt = 0; nt < 4; ++nt) {
                float v = acc[nt][r] + b1v[nt] + dr * w1c[nt];
                float hh = v / (1.f + __expf(-v));  // silu
                p = fmaf(hh, w2v[nt], p);
            }
            // reduce over the 16 lanes of this quad (j dimension)
            p += __shfl_xor(p, 1);
            p += __shfl_xor(p, 2);
            p += __shfl_xor(p, 4);
            p += __shfl_xor(p, 8);
            const float s = p + b2;
            att[r] = (1.f / (1.f + __expf(-s))) * emask[e] * NORM_INV;
        }

        // Scatter: agg[row[e]] += x[col[e]] * att[e], lane = feature index.
#pragma unroll
        for (int el = 0; el < 16; ++el) {
            const int qq = el >> 2, rr = el & 3;
            const float av = __shfl(att[rr], qq * 16);
            const int colv = __shfl(ec, el);
            const int rowv = __shfl(er, el);
            const float xv = xf[(size_t)colv * DIM + lane];
            atomicAdd(&agg[(size_t)rowv * DIM + lane], xv * av);
        }
    }
}

// ---------------------------------------------------------------------------
// Kernel 3: out = silu(LN(x + agg))   (agg already scaled by 1/100)
// One wave per row; lane = feature index.
// ---------------------------------------------------------------------------
__global__ __launch_bounds__(256) void ln_kernel(
    const float* __restrict__ xf, const float* __restrict__ agg,
    const float* __restrict__ g, const float* __restrict__ b,
    float* __restrict__ out) {
    const int lane = threadIdx.x & 63;
    const int wv = threadIdx.x >> 6;
    const int n = blockIdx.x * 4 + wv;
    const size_t base = (size_t)n * DIM + lane;

    float o = xf[base] + agg[base];
    float s = o;
#pragma unroll
    for (int off = 1; off < 64; off <<= 1) s += __shfl_xor(s, off);
    const float mu = s * (1.f / 64.f);
    const float d = o - mu;
    float v = d * d;
#pragma unroll
    for (int off = 1; off < 64; off <<= 1) v += __shfl_xor(v, off);
    const float var = v * (1.f / 64.f);
    const float y = d * rsqrtf(var + LN_EPS) * g[lane] + b[lane];
    out[base] = y / (1.f + __expf(-y));
}

extern "C" void kernel_launch(void* const* d_in, const int* in_sizes, int n_in,
                              void* d_out, int out_size, void* d_ws, size_t ws_size,
                              hipStream_t stream) {
    const float* h      = (const float*)d_in[0];
    const float* dist   = (const float*)d_in[1];
    const int*   edges  = (const int*)d_in[2];
    // d_in[3] node_mask: unused by the reference
    const float* emask  = (const float*)d_in[4];
    const float* W_lin  = (const float*)d_in[5];
    const float* b_lin  = (const float*)d_in[6];
    const float* att_W1 = (const float*)d_in[7];
    const float* att_b1 = (const float*)d_in[8];
    const float* att_W2 = (const float*)d_in[9];
    const float* att_b2 = (const float*)d_in[10];
    const float* ln_g   = (const float*)d_in[11];
    const float* ln_b   = (const float*)d_in[12];
    float* out = (float*)d_out;

    char* ws = (char*)d_ws;
    float* xf  = (float*)ws;                                    // N*64 f32
    float* agg = (float*)(ws + (size_t)N_NODES * DIM * 4);      // N*64 f32
    unsigned short* xbf =
        (unsigned short*)(ws + (size_t)N_NODES * DIM * 8);      // N*64 bf16

    hipMemsetAsync(agg, 0, (size_t)N_NODES * DIM * sizeof(float), stream);
    proj_kernel<<<N_NODES / 16, 256, 0, stream>>>(h, W_lin, b_lin, xf, xbf);
    edge_kernel<<<2048, 256, 0, stream>>>(edges, dist, emask, att_W1, att_b1,
                                          att_W2, att_b2, xf, xbf, agg);
    ln_kernel<<<N_NODES / 4, 256, 0, stream>>>(xf, agg, ln_g, ln_b, out);
}

// Round 2
// 385.796 us; speedup vs baseline: 1.0945x; 1.0945x over previous
//
#include <hip/hip_runtime.h>
#include <hip/hip_bf16.h>

#define N_NODES 100000
#define N_EDGES 1000000
#define DIM 64
#define NORM_INV 0.01f
#define LN_EPS 1e-5f

typedef __attribute__((ext_vector_type(4))) float f32x4;

__device__ __forceinline__ unsigned short f2bf(float f) {
    union { float f; unsigned u; } x; x.f = f;
    unsigned r = x.u + 0x7FFFu + ((x.u >> 16) & 1u);
    return (unsigned short)(r >> 16);
}
__device__ __forceinline__ float bf2f(unsigned short s) {
    union { unsigned u; float f; } x; x.u = ((unsigned)s) << 16; return x.f;
}

// ---------------------------------------------------------------------------
// K1: fused projection. Stage 1: x = h @ W_lin^T + b_lin (16 rows/block).
// Stage 2: u = x @ W1a^T, v = x @ W1b^T  (W1a/W1b = first/second 64 cols of
// att_W1). Writes packed bf16 node record xv[n] = [x(64) | v(64)] and u_bf[n].
// ---------------------------------------------------------------------------
__global__ __launch_bounds__(256) void proj_fused(
    const float* __restrict__ h, const float* __restrict__ W,
    const float* __restrict__ bl, const float* __restrict__ att_W1,
    unsigned short* __restrict__ xv, unsigned short* __restrict__ u_bf) {
    __shared__ __align__(16) float Wa[64 * 68];
    __shared__ __align__(16) float Wb[64 * 68];
    __shared__ __align__(16) float hs[16 * 68];
    __shared__ __align__(16) float xs[16 * 68];
    const int tid = threadIdx.x;
    const int lane = tid & 63;
    const int wv = tid >> 6;
    const int n0 = blockIdx.x * 16 + wv * 4;

    // Stage 1: W_lin into Wa, h rows into hs
    for (int i = tid; i < 4096; i += 256) {
        int r = i >> 6, c = i & 63;
        Wa[r * 68 + c] = W[i];
    }
#pragma unroll
    for (int r = 0; r < 4; ++r)
        hs[(wv * 4 + r) * 68 + lane] = h[(size_t)(n0 + r) * DIM + lane];
    __syncthreads();

    float bj = bl[lane];
    float acc[4] = {bj, bj, bj, bj};
#pragma unroll
    for (int k4 = 0; k4 < 16; ++k4) {
        f32x4 w4 = *(const f32x4*)&Wa[lane * 68 + k4 * 4];
#pragma unroll
        for (int r = 0; r < 4; ++r) {
            f32x4 h4 = *(const f32x4*)&hs[(wv * 4 + r) * 68 + k4 * 4];
            acc[r] = fmaf(w4[0], h4[0], acc[r]);
            acc[r] = fmaf(w4[1], h4[1], acc[r]);
            acc[r] = fmaf(w4[2], h4[2], acc[r]);
            acc[r] = fmaf(w4[3], h4[3], acc[r]);
        }
    }
#pragma unroll
    for (int r = 0; r < 4; ++r) {
        xs[(wv * 4 + r) * 68 + lane] = acc[r];
        xv[(size_t)(n0 + r) * 128 + lane] = f2bf(acc[r]);
    }
    __syncthreads();

    // Stage 2: att_W1 columns 0..63 -> Wa, 64..127 -> Wb
    for (int i = tid; i < 4096; i += 256) {
        int r = i >> 6, c = i & 63;
        Wa[r * 68 + c] = att_W1[r * 129 + c];
        Wb[r * 68 + c] = att_W1[r * 129 + 64 + c];
    }
    __syncthreads();

    float ua[4] = {0.f, 0.f, 0.f, 0.f};
    float va[4] = {0.f, 0.f, 0.f, 0.f};
#pragma unroll
    for (int k4 = 0; k4 < 16; ++k4) {
        f32x4 wa = *(const f32x4*)&Wa[lane * 68 + k4 * 4];
        f32x4 wb = *(const f32x4*)&Wb[lane * 68 + k4 * 4];
#pragma unroll
        for (int r = 0; r < 4; ++r) {
            f32x4 x4 = *(const f32x4*)&xs[(wv * 4 + r) * 68 + k4 * 4];
            ua[r] = fmaf(wa[0], x4[0], ua[r]); ua[r] = fmaf(wa[1], x4[1], ua[r]);
            ua[r] = fmaf(wa[2], x4[2], ua[r]); ua[r] = fmaf(wa[3], x4[3], ua[r]);
            va[r] = fmaf(wb[0], x4[0], va[r]); va[r] = fmaf(wb[1], x4[1], va[r]);
            va[r] = fmaf(wb[2], x4[2], va[r]); va[r] = fmaf(wb[3], x4[3], va[r]);
        }
    }
#pragma unroll
    for (int r = 0; r < 4; ++r) {
        u_bf[(size_t)(n0 + r) * 64 + lane] = f2bf(ua[r]);
        xv[(size_t)(n0 + r) * 128 + 64 + lane] = f2bf(va[r]);
    }
}

// ---------------------------------------------------------------------------
// K2: histogram of destination rows
// ---------------------------------------------------------------------------
__global__ __launch_bounds__(256) void hist_kernel(
    const int* __restrict__ edges, int* __restrict__ cnt) {
    int e = blockIdx.x * 256 + threadIdx.x;
    if (e < N_EDGES) atomicAdd(&cnt[edges[e]], 1);
}

// ---------------------------------------------------------------------------
// K3a/b/c: exclusive prefix sum of cnt -> start (hierarchical)
// ---------------------------------------------------------------------------
__global__ __launch_bounds__(1024) void scan_block(
    const int* __restrict__ cnt, int* __restrict__ start, int* __restrict__ bsum) {
    __shared__ int sm[1024];
    const int t = threadIdx.x;
    const int i = blockIdx.x * 1024 + t;
    int v = (i < N_NODES) ? cnt[i] : 0;
    sm[t] = v;
    __syncthreads();
#pragma unroll
    for (int off = 1; off < 1024; off <<= 1) {
        int a = (t >= off) ? sm[t - off] : 0;
        __syncthreads();
        sm[t] += a;
        __syncthreads();
    }
    if (i < N_NODES) start[i] = sm[t] - v;  // exclusive
    if (t == 1023) bsum[blockIdx.x] = sm[1023];
}

__global__ __launch_bounds__(128) void scan_top(
    const int* __restrict__ bsum, int* __restrict__ boff, int nb) {
    __shared__ int sm[128];
    const int t = threadIdx.x;
    int v = (t < nb) ? bsum[t] : 0;
    sm[t] = v;
    __syncthreads();
#pragma unroll
    for (int off = 1; off < 128; off <<= 1) {
        int a = (t >= off) ? sm[t - off] : 0;
        __syncthreads();
        sm[t] += a;
        __syncthreads();
    }
    boff[t] = sm[t] - v;  // exclusive
}

__global__ __launch_bounds__(1024) void scan_add(
    int* __restrict__ start, const int* __restrict__ boff,
    int* __restrict__ cursor) {
    const int i = blockIdx.x * 1024 + threadIdx.x;
    if (i < N_NODES) {
        int s = start[i] + boff[blockIdx.x];
        start[i] = s;
        cursor[i] = s;
    }
    if (i == 0) start[N_NODES] = N_EDGES;
}

// ---------------------------------------------------------------------------
// K4: scatter edges into row-sorted order. One 16B record per edge:
// {col, dist, emask, 0}
// ---------------------------------------------------------------------------
__global__ __launch_bounds__(256) void scatter_kernel(
    const int* __restrict__ edges, const float* __restrict__ dist,
    const float* __restrict__ emask, int* __restrict__ cursor,
    int4* __restrict__ recs) {
    int e = blockIdx.x * 256 + threadIdx.x;
    if (e < N_EDGES) {
        int r = edges[e];
        int pos = atomicAdd(&cursor[r], 1);
        int4 rc;
        rc.x = edges[N_EDGES + e];
        rc.y = __float_as_int(dist[e]);
        rc.z = __float_as_int(emask[e]);
        rc.w = 0;
        recs[pos] = rc;
    }
}

// ---------------------------------------------------------------------------
// K5: fused per-row aggregation + residual + LayerNorm + SiLU.
// One wave per row, lane = feature. Per edge: gather {x,v}[col] (bf16),
// hdn = silu(u[row]+v[col]+dist*w1c+b1); att = sigmoid(dot(hdn,w2)+b2);
// acc += att*emask/100 * x[col]. Edges processed in chunks of 4 for MLP.
// ---------------------------------------------------------------------------
__global__ __launch_bounds__(256) void agg_ln_kernel(
    const int* __restrict__ start, const int4* __restrict__ recs,
    const unsigned short* __restrict__ xv, const unsigned short* __restrict__ u_bf,
    const float* __restrict__ att_W1, const float* __restrict__ att_b1,
    const float* __restrict__ att_W2, const float* __restrict__ att_b2,
    const float* __restrict__ ln_g, const float* __restrict__ ln_b,
    float* __restrict__ out) {
    const int lane = threadIdx.x & 63;
    const int wv = threadIdx.x >> 6;
    const int r = blockIdx.x * 4 + wv;

    const float b1v = att_b1[lane];
    const float w2v = att_W2[lane];
    const float w1c = att_W1[lane * 129 + 128];
    const float b2v = att_b2[0];

    const int s = start[r];
    const int e_end = start[r + 1];
    const float uu = bf2f(u_bf[(size_t)r * 64 + lane]);

    float acc = 0.f;
    for (int e = s; e < e_end; e += 4) {
        int4 rec[4];
#pragma unroll
        for (int i = 0; i < 4; ++i) {
            const bool ok = (e + i < e_end);
            rec[i] = recs[ok ? (e + i) : s];
            if (!ok) rec[i].z = 0;  // emask -> 0 kills the contribution
        }
        unsigned short xq[4], vq[4];
#pragma unroll
        for (int i = 0; i < 4; ++i) {
            const unsigned short* p = xv + (size_t)rec[i].x * 128 + lane;
            xq[i] = p[0];
            vq[i] = p[64];
        }
#pragma unroll
        for (int i = 0; i < 4; ++i) {
            float pre = uu + bf2f(vq[i]) + __int_as_float(rec[i].y) * w1c + b1v;
            float t = pre / (1.f + __expf(-pre));  // silu
            float pv = t * w2v;
#pragma unroll
            for (int off = 1; off < 64; off <<= 1) pv += __shfl_xor(pv, off);
            const float att =
                __int_as_float(rec[i].z) * NORM_INV / (1.f + __expf(-(pv + b2v)));
            acc = fmaf(att, bf2f(xq[i]), acc);
        }
    }

    // residual + LN + silu
    float o = bf2f(xv[(size_t)r * 128 + lane]) + acc;
    float sm = o;
#pragma unroll
    for (int off = 1; off < 64; off <<= 1) sm += __shfl_xor(sm, off);
    const float mu = sm * (1.f / 64.f);
    const float d = o - mu;
    float vv = d * d;
#pragma unroll
    for (int off = 1; off < 64; off <<= 1) vv += __shfl_xor(vv, off);
    const float y = d * rsqrtf(vv * (1.f / 64.f) + LN_EPS) * ln_g[lane] + ln_b[lane];
    out[(size_t)r * 64 + lane] = y / (1.f + __expf(-y));
}

extern "C" void kernel_launch(void* const* d_in, const int* in_sizes, int n_in,
                              void* d_out, int out_size, void* d_ws, size_t ws_size,
                              hipStream_t stream) {
    const float* h      = (const float*)d_in[0];
    const float* dist   = (const float*)d_in[1];
    const int*   edges  = (const int*)d_in[2];
    // d_in[3] node_mask: unused by the reference
    const float* emask  = (const float*)d_in[4];
    const float* W_lin  = (const float*)d_in[5];
    const float* b_lin  = (const float*)d_in[6];
    const float* att_W1 = (const float*)d_in[7];
    const float* att_b1 = (const float*)d_in[8];
    const float* att_W2 = (const float*)d_in[9];
    const float* att_b2 = (const float*)d_in[10];
    const float* ln_g   = (const float*)d_in[11];
    const float* ln_b   = (const float*)d_in[12];
    float* out = (float*)d_out;

    char* ws = (char*)d_ws;
    unsigned short* xv   = (unsigned short*)ws;                   // N*128 bf16
    unsigned short* u_bf = (unsigned short*)(ws + 25600000);      // N*64 bf16
    int4* recs           = (int4*)(ws + 38400000);                // E*16 B
    int*  cnt            = (int*)(ws + 54400000);                 // N
    int*  start          = (int*)(ws + 54800128);                 // N+1
    int*  cursor         = (int*)(ws + 55200256);                 // N
    int*  bsum           = (int*)(ws + 55600384);                 // <=128
    int*  boff           = (int*)(ws + 55600896);                 // <=128

    const int NB = (N_NODES + 1023) / 1024;  // 98

    hipMemsetAsync(cnt, 0, N_NODES * sizeof(int), stream);
    proj_fused<<<N_NODES / 16, 256, 0, stream>>>(h, W_lin, b_lin, att_W1, xv, u_bf);
    hist_kernel<<<(N_EDGES + 255) / 256, 256, 0, stream>>>(edges, cnt);
    scan_block<<<NB, 1024, 0, stream>>>(cnt, start, bsum);
    scan_top<<<1, 128, 0, stream>>>(bsum, boff, NB);
    scan_add<<<NB, 1024, 0, stream>>>(start, boff, cursor);
    scatter_kernel<<<(N_EDGES + 255) / 256, 256, 0, stream>>>(edges, dist, emask,
                                                              cursor, recs);
    agg_ln_kernel<<<N_NODES / 4, 256, 0, stream>>>(start, recs, xv, u_bf, att_W1,
                                                   att_b1, att_W2, att_b2,
                                                   ln_g, ln_b, out);
}

// Round 3
// 315.911 us; speedup vs baseline: 1.3367x; 1.2212x over previous
//
#include <hip/hip_runtime.h>
#include <hip/hip_bf16.h>

#define N_NODES 100000
#define N_EDGES 1000000
#define DIM 64
#define NORM_INV 0.01f
#define LN_EPS 1e-5f

typedef __attribute__((ext_vector_type(8))) short short8;
typedef __attribute__((ext_vector_type(4))) float f32x4;

__device__ __forceinline__ unsigned short f2bf(float f) {
    union { float f; unsigned u; } x; x.f = f;
    unsigned r = x.u + 0x7FFFu + ((x.u >> 16) & 1u);
    return (unsigned short)(r >> 16);
}
__device__ __forceinline__ float bf2f(unsigned short s) {
    union { unsigned u; float f; } x; x.u = ((unsigned)s) << 16; return x.f;
}

// ---------------------------------------------------------------------------
// P: MFMA projection. Per 16-node tile:
//   x = h @ W_lin^T + b  (hi/lo bf16 split: Ahi*Whi + Ahi*Wlo + Alo*Whi ~= f32)
//   u = x @ W1a^T, v = x @ W1b^T (plain bf16 MFMA, A re-read via LDS transpose)
// Outputs: xv record per node (256 B): for j in 0..15: x{j,j+16,j+32,j+48} bf16,
// v{...} bf16 interleaved 16 B;  u_perm f32: u_perm[n][j*4+k] = u[n][j+16k].
// Each wave does 4 tiles; no __syncthreads (per-wave LDS regions).
// ---------------------------------------------------------------------------
__global__ __launch_bounds__(256) void proj_mfma(
    const float* __restrict__ h, const float* __restrict__ W,
    const float* __restrict__ bl, const float* __restrict__ att_W1,
    unsigned short* __restrict__ xv, float* __restrict__ u_perm) {
    __shared__ __align__(16) unsigned short lds[4][16 * 72];
    const int lane = threadIdx.x & 63;
    const int wv = threadIdx.x >> 6;
    const int c = lane & 15, q = lane >> 4;

    short8 Whi[4][2], Wlo[4][2], Wa[4][2], Wb[4][2];
    float bias[4];
#pragma unroll
    for (int nt = 0; nt < 4; ++nt) {
        const int n = nt * 16 + c;
        bias[nt] = bl[n];
#pragma unroll
        for (int ks = 0; ks < 2; ++ks) {
            const int k0 = ks * 32 + q * 8;
            short8 hi8, lo8, a8, b8;
#pragma unroll
            for (int jj = 0; jj < 8; ++jj) {
                float w = W[n * 64 + k0 + jj];
                unsigned short hh = f2bf(w);
                hi8[jj] = (short)hh;
                lo8[jj] = (short)f2bf(w - bf2f(hh));
                a8[jj] = (short)f2bf(att_W1[n * 129 + k0 + jj]);
                b8[jj] = (short)f2bf(att_W1[n * 129 + 64 + k0 + jj]);
            }
            Whi[nt][ks] = hi8; Wlo[nt][ks] = lo8;
            Wa[nt][ks] = a8;   Wb[nt][ks] = b8;
        }
    }

    unsigned short* lw = lds[wv];
    for (int t = 0; t < 4; ++t) {
        const int tile = (blockIdx.x * 4 + wv) * 4 + t;
        if (tile >= N_NODES / 16) break;
        const int n0 = tile * 16;

        // A (h rows) hi/lo bf16
        short8 Ahi[2], Alo[2];
#pragma unroll
        for (int ks = 0; ks < 2; ++ks) {
            const float* hp = h + (size_t)(n0 + c) * 64 + ks * 32 + q * 8;
            f32x4 p0 = *(const f32x4*)hp;
            f32x4 p1 = *(const f32x4*)(hp + 4);
            short8 hi8, lo8;
#pragma unroll
            for (int jj = 0; jj < 4; ++jj) {
                unsigned short hh = f2bf(p0[jj]);
                hi8[jj] = (short)hh; lo8[jj] = (short)f2bf(p0[jj] - bf2f(hh));
                unsigned short h2 = f2bf(p1[jj]);
                hi8[4 + jj] = (short)h2; lo8[4 + jj] = (short)f2bf(p1[jj] - bf2f(h2));
            }
            Ahi[ks] = hi8; Alo[ks] = lo8;
        }

        f32x4 xacc[4] = {{0,0,0,0},{0,0,0,0},{0,0,0,0},{0,0,0,0}};
#pragma unroll
        for (int ks = 0; ks < 2; ++ks)
#pragma unroll
            for (int nt = 0; nt < 4; ++nt) {
                xacc[nt] = __builtin_amdgcn_mfma_f32_16x16x32_bf16(Ahi[ks], Whi[nt][ks], xacc[nt], 0, 0, 0);
                xacc[nt] = __builtin_amdgcn_mfma_f32_16x16x32_bf16(Ahi[ks], Wlo[nt][ks], xacc[nt], 0, 0, 0);
                xacc[nt] = __builtin_amdgcn_mfma_f32_16x16x32_bf16(Alo[ks], Whi[nt][ks], xacc[nt], 0, 0, 0);
            }

        // epilogue: bias, bf16, write LDS tile (row-major) + xv x-part (permuted)
#pragma unroll
        for (int r = 0; r < 4; ++r) {
            const int node = n0 + q * 4 + r;
            unsigned short xb[4];
#pragma unroll
            for (int nt = 0; nt < 4; ++nt) {
                unsigned short v16 = f2bf(xacc[nt][r] + bias[nt]);
                xb[nt] = v16;
                lw[(q * 4 + r) * 72 + nt * 16 + c] = v16;
            }
            uint2 pk;
            pk.x = (unsigned)xb[0] | ((unsigned)xb[1] << 16);
            pk.y = (unsigned)xb[2] | ((unsigned)xb[3] << 16);
            *(uint2*)(xv + (size_t)node * 128 + c * 8) = pk;
        }

        // phase 2: A = x tile from LDS (row-major), compute u, v
        short8 Ax[2];
#pragma unroll
        for (int ks = 0; ks < 2; ++ks)
            Ax[ks] = *(const short8*)&lw[c * 72 + ks * 32 + q * 8];

        f32x4 uacc[4] = {{0,0,0,0},{0,0,0,0},{0,0,0,0},{0,0,0,0}};
        f32x4 vacc[4] = {{0,0,0,0},{0,0,0,0},{0,0,0,0},{0,0,0,0}};
#pragma unroll
        for (int ks = 0; ks < 2; ++ks)
#pragma unroll
            for (int nt = 0; nt < 4; ++nt) {
                uacc[nt] = __builtin_amdgcn_mfma_f32_16x16x32_bf16(Ax[ks], Wa[nt][ks], uacc[nt], 0, 0, 0);
                vacc[nt] = __builtin_amdgcn_mfma_f32_16x16x32_bf16(Ax[ks], Wb[nt][ks], vacc[nt], 0, 0, 0);
            }
#pragma unroll
        for (int r = 0; r < 4; ++r) {
            const int node = n0 + q * 4 + r;
            f32x4 uo = {uacc[0][r], uacc[1][r], uacc[2][r], uacc[3][r]};
            *(f32x4*)(u_perm + (size_t)node * 64 + c * 4) = uo;
            uint2 pk;
            pk.x = (unsigned)f2bf(vacc[0][r]) | ((unsigned)f2bf(vacc[1][r]) << 16);
            pk.y = (unsigned)f2bf(vacc[2][r]) | ((unsigned)f2bf(vacc[3][r]) << 16);
            *(uint2*)(xv + (size_t)node * 128 + c * 8 + 4) = pk;
        }
    }
}

// ---------------------------------------------------------------------------
// hist / scan / scatter (counting sort by destination row)
// ---------------------------------------------------------------------------
__global__ __launch_bounds__(256) void hist_kernel(
    const int* __restrict__ edges, int* __restrict__ cnt) {
    int e = blockIdx.x * 256 + threadIdx.x;
    if (e < N_EDGES) atomicAdd(&cnt[edges[e]], 1);
}

__global__ __launch_bounds__(1024) void scan_block(
    const int* __restrict__ cnt, int* __restrict__ start, int* __restrict__ bsum) {
    __shared__ int sm[1024];
    const int t = threadIdx.x;
    const int i = blockIdx.x * 1024 + t;
    int v = (i < N_NODES) ? cnt[i] : 0;
    sm[t] = v;
    __syncthreads();
#pragma unroll
    for (int off = 1; off < 1024; off <<= 1) {
        int a = (t >= off) ? sm[t - off] : 0;
        __syncthreads();
        sm[t] += a;
        __syncthreads();
    }
    if (i < N_NODES) start[i] = sm[t] - v;
    if (t == 1023) bsum[blockIdx.x] = sm[1023];
}

__global__ __launch_bounds__(1024) void scan_add(
    int* __restrict__ start, const int* __restrict__ bsum,
    int* __restrict__ cursor) {
    __shared__ int partial[2];
    const int t = threadIdx.x;
    if (t < 128) {
        int v = (t < blockIdx.x) ? bsum[t] : 0;  // NB=98 < 128
#pragma unroll
        for (int off = 1; off < 64; off <<= 1) v += __shfl_xor(v, off);
        if ((t & 63) == 0) partial[t >> 6] = v;
    }
    __syncthreads();
    const int off = partial[0] + partial[1];
    const int i = blockIdx.x * 1024 + t;
    if (i < N_NODES) {
        int s = start[i] + off;
        start[i] = s;
        cursor[i] = s;
    }
    if (blockIdx.x == 0 && t == 0) start[N_NODES] = N_EDGES;
}

// 8 B record per edge: {col, dist(bf16 lo) | emask*0.01(bf16 hi)}
__global__ __launch_bounds__(256) void scatter_kernel(
    const int* __restrict__ edges, const float* __restrict__ dist,
    const float* __restrict__ emask, int* __restrict__ cursor,
    uint2* __restrict__ recs) {
    int e = blockIdx.x * 256 + threadIdx.x;
    if (e < N_EDGES) {
        int r = edges[e];
        int pos = atomicAdd(&cursor[r], 1);
        uint2 rc;
        rc.x = (unsigned)edges[N_EDGES + e];
        rc.y = (unsigned)f2bf(dist[e]) | ((unsigned)f2bf(emask[e] * NORM_INV) << 16);
        recs[pos] = rc;
    }
}

// ---------------------------------------------------------------------------
// agg: one wave per row. lane = slot(s=lane>>4)*16 + j(lane&15).
// Lane owns features {j, j+16, j+32, j+48} of its slot's edge.
// Per 4 edges: 1 rec load + 1 dwordx4 gather + 4-level 16-lane reduction.
// Depth-2 rec / depth-1 gather software pipeline. Fused residual+LN+SiLU.
// ---------------------------------------------------------------------------
__global__ __launch_bounds__(256, 8) void agg_ln_kernel(
    const int* __restrict__ start, const uint2* __restrict__ recs,
    const unsigned short* __restrict__ xv, const float* __restrict__ u_perm,
    const float* __restrict__ att_b1, const float* __restrict__ att_W1,
    const float* __restrict__ att_W2, const float* __restrict__ att_b2,
    const float* __restrict__ ln_g, const float* __restrict__ ln_b,
    float* __restrict__ out) {
    const int lane = threadIdx.x & 63;
    const int wv = threadIdx.x >> 6;
    const int j = lane & 15;
    const int s = lane >> 4;
    const int r = blockIdx.x * 4 + wv;

    float w2v[4], w1cv[4], base[4];
    const f32x4 u4 = *(const f32x4*)(u_perm + (size_t)r * 64 + j * 4);
#pragma unroll
    for (int k = 0; k < 4; ++k) {
        const int f = j + 16 * k;
        w2v[k] = att_W2[f];
        w1cv[k] = att_W1[f * 129 + 128];
        base[k] = u4[k] + att_b1[f];
    }
    const float b2 = att_b2[0];

    const int s0 = start[r];
    const int e1 = start[r + 1];
    const unsigned* xvu = (const unsigned*)xv;

    float a0 = 0.f, a1 = 0.f, a2 = 0.f, a3 = 0.f;
    if (e1 > s0) {
        int idx = s0 + s; if (idx >= e1) idx = e1 - 1;
        uint2 recA = recs[idx];
        uint4 xvA = *(const uint4*)(xvu + (size_t)recA.x * 64 + j * 4);
        idx = s0 + 4 + s; if (idx >= e1) idx = e1 - 1;
        uint2 recB = recs[idx];
        for (int e = s0; e < e1; e += 4) {
            int idc = e + 8 + s; if (idc >= e1) idc = e1 - 1;
            uint2 recC = recs[idc];
            uint4 xvB = *(const uint4*)(xvu + (size_t)recB.x * 64 + j * 4);

            const float dist = __uint_as_float(recA.y << 16);
            const float emN = ((e + s) < e1) ? __uint_as_float(recA.y & 0xffff0000u) : 0.f;
            const float x0 = __uint_as_float(xvA.x << 16);
            const float x1 = __uint_as_float(xvA.x & 0xffff0000u);
            const float x2 = __uint_as_float(xvA.y << 16);
            const float x3 = __uint_as_float(xvA.y & 0xffff0000u);
            const float v0 = __uint_as_float(xvA.z << 16);
            const float v1 = __uint_as_float(xvA.z & 0xffff0000u);
            const float v2 = __uint_as_float(xvA.w << 16);
            const float v3 = __uint_as_float(xvA.w & 0xffff0000u);
            float pv = 0.f, pre, t;
            pre = fmaf(dist, w1cv[0], base[0]) + v0; t = pre / (1.f + __expf(-pre)); pv = fmaf(t, w2v[0], pv);
            pre = fmaf(dist, w1cv[1], base[1]) + v1; t = pre / (1.f + __expf(-pre)); pv = fmaf(t, w2v[1], pv);
            pre = fmaf(dist, w1cv[2], base[2]) + v2; t = pre / (1.f + __expf(-pre)); pv = fmaf(t, w2v[2], pv);
            pre = fmaf(dist, w1cv[3], base[3]) + v3; t = pre / (1.f + __expf(-pre)); pv = fmaf(t, w2v[3], pv);
            pv += __shfl_xor(pv, 1); pv += __shfl_xor(pv, 2);
            pv += __shfl_xor(pv, 4); pv += __shfl_xor(pv, 8);
            const float att = emN / (1.f + __expf(-(pv + b2)));
            a0 = fmaf(att, x0, a0); a1 = fmaf(att, x1, a1);
            a2 = fmaf(att, x2, a2); a3 = fmaf(att, x3, a3);
            recA = recB; xvA = xvB; recB = recC;
        }
    }
    // combine partial accs across the 4 slots
    a0 += __shfl_xor(a0, 16); a0 += __shfl_xor(a0, 32);
    a1 += __shfl_xor(a1, 16); a1 += __shfl_xor(a1, 32);
    a2 += __shfl_xor(a2, 16); a2 += __shfl_xor(a2, 32);
    a3 += __shfl_xor(a3, 16); a3 += __shfl_xor(a3, 32);

    // residual from own record's x-part
    const uint2 xr = *(const uint2*)(xvu + (size_t)r * 64 + j * 4);
    const float o0 = __uint_as_float(xr.x << 16) + a0;
    const float o1 = __uint_as_float(xr.x & 0xffff0000u) + a1;
    const float o2 = __uint_as_float(xr.y << 16) + a2;
    const float o3 = __uint_as_float(xr.y & 0xffff0000u) + a3;

    float ssum = o0 + o1 + o2 + o3;
    ssum += __shfl_xor(ssum, 1); ssum += __shfl_xor(ssum, 2);
    ssum += __shfl_xor(ssum, 4); ssum += __shfl_xor(ssum, 8);
    const float mu = ssum * (1.f / 64.f);
    const float d0 = o0 - mu, d1 = o1 - mu, d2 = o2 - mu, d3 = o3 - mu;
    float vs = d0 * d0 + d1 * d1 + d2 * d2 + d3 * d3;
    vs += __shfl_xor(vs, 1); vs += __shfl_xor(vs, 2);
    vs += __shfl_xor(vs, 4); vs += __shfl_xor(vs, 8);
    const float rstd = rsqrtf(vs * (1.f / 64.f) + LN_EPS);

    float y;
    {
        const int f = j + 16 * s;
        const float dk = (s == 0) ? d0 : (s == 1) ? d1 : (s == 2) ? d2 : d3;
        y = fmaf(dk * rstd, ln_g[f], ln_b[f]);
    }
    out[(size_t)r * 64 + lane] = y / (1.f + __expf(-y));
}

extern "C" void kernel_launch(void* const* d_in, const int* in_sizes, int n_in,
                              void* d_out, int out_size, void* d_ws, size_t ws_size,
                              hipStream_t stream) {
    const float* h      = (const float*)d_in[0];
    const float* dist   = (const float*)d_in[1];
    const int*   edges  = (const int*)d_in[2];
    const float* emask  = (const float*)d_in[4];
    const float* W_lin  = (const float*)d_in[5];
    const float* b_lin  = (const float*)d_in[6];
    const float* att_W1 = (const float*)d_in[7];
    const float* att_b1 = (const float*)d_in[8];
    const float* att_W2 = (const float*)d_in[9];
    const float* att_b2 = (const float*)d_in[10];
    const float* ln_g   = (const float*)d_in[11];
    const float* ln_b   = (const float*)d_in[12];
    float* out = (float*)d_out;

    char* ws = (char*)d_ws;
    unsigned short* xv = (unsigned short*)ws;                 // 25.6 MB
    float* u_perm = (float*)(ws + 25600000);                  // 25.6 MB
    uint2* recs   = (uint2*)(ws + 51200000);                  // 8 MB
    int* cnt      = (int*)(ws + 59200000);                    // 400 KB
    int* start    = (int*)(ws + 59600000);                    // 400 KB + 4
    int* cursor   = (int*)(ws + 60000128);                    // 400 KB
    int* bsum     = (int*)(ws + 60400128);                    // 512 B

    const int NB = (N_NODES + 1023) / 1024;  // 98

    hipMemsetAsync(cnt, 0, N_NODES * sizeof(int), stream);
    proj_mfma<<<391, 256, 0, stream>>>(h, W_lin, b_lin, att_W1, xv, u_perm);
    hist_kernel<<<(N_EDGES + 255) / 256, 256, 0, stream>>>(edges, cnt);
    scan_block<<<NB, 1024, 0, stream>>>(cnt, start, bsum);
    scan_add<<<NB, 1024, 0, stream>>>(start, bsum, cursor);
    scatter_kernel<<<(N_EDGES + 255) / 256, 256, 0, stream>>>(edges, dist, emask,
                                                              cursor, recs);
    agg_ln_kernel<<<N_NODES / 4, 256, 0, stream>>>(start, recs, xv, u_perm,
                                                   att_b1, att_W1, att_W2, att_b2,
                                                   ln_g, ln_b, out);
}

// Round 4
// 288.419 us; speedup vs baseline: 1.4641x; 1.0953x over previous
//
#include <hip/hip_runtime.h>
#include <hip/hip_bf16.h>

#define N_NODES 100000
#define N_EDGES 1000000
#define DIM 64
#define NORM_INV 0.01f
#define LN_EPS 1e-5f
#define N_TILES 6250          // N_NODES/16
#define PROJ_BLOCKS 1563      // ceil(6250/4)
#define HIST_BLOCKS 3907      // ceil(1e6/256)

typedef __attribute__((ext_vector_type(8))) short short8;
typedef __attribute__((ext_vector_type(4))) float f32x4;

__device__ __forceinline__ unsigned short f2bf(float f) {
    union { float f; unsigned u; } x; x.f = f;
    unsigned r = x.u + 0x7FFFu + ((x.u >> 16) & 1u);
    return (unsigned short)(r >> 16);
}
__device__ __forceinline__ float bf2f(unsigned short s) {
    union { unsigned u; float f; } x; x.u = ((unsigned)s) << 16; return x.f;
}

// ---------------------------------------------------------------------------
// P0: precompute MFMA weight fragments (lane-ordered) into ws. One block.
// Layout: frag[(nt*2+ks)*64 + lane] as short8 -> proj loads are coalesced.
// ---------------------------------------------------------------------------
__global__ __launch_bounds__(256) void prep_frags(
    const float* __restrict__ W, const float* __restrict__ att_W1,
    short8* __restrict__ whi, short8* __restrict__ wlo,
    short8* __restrict__ wa, short8* __restrict__ wb) {
    const int l = threadIdx.x & 63;
    const int nt = threadIdx.x >> 6;
    const int c = l & 15, q = l >> 4;
    const int n = nt * 16 + c;
#pragma unroll
    for (int ks = 0; ks < 2; ++ks) {
        const int k0 = ks * 32 + q * 8;
        short8 hi8, lo8, a8, b8;
#pragma unroll
        for (int jj = 0; jj < 8; ++jj) {
            float w = W[n * 64 + k0 + jj];
            unsigned short hh = f2bf(w);
            hi8[jj] = (short)hh;
            lo8[jj] = (short)f2bf(w - bf2f(hh));
            a8[jj] = (short)f2bf(att_W1[n * 129 + k0 + jj]);
            b8[jj] = (short)f2bf(att_W1[n * 129 + 64 + k0 + jj]);
        }
        const int idx = (nt * 2 + ks) * 64 + l;
        whi[idx] = hi8; wlo[idx] = lo8; wa[idx] = a8; wb[idx] = b8;
    }
}

// ---------------------------------------------------------------------------
// P1 (fat kernel): blocks [0,1563): MFMA projection, 1 tile (16 nodes)/wave.
//   x = h@W^T + b (hi/lo bf16 split ~= f32), u = x@W1a^T, v = x@W1b^T.
//   Outputs: xv[node] 256B = interleaved {x4|v4} bf16 per j; u_bf bf16 permuted.
// blocks [1563, 5470): histogram of destination rows.
// ---------------------------------------------------------------------------
__global__ __launch_bounds__(256) void proj_hist(
    const float* __restrict__ h, const float* __restrict__ bl,
    const short8* __restrict__ whi, const short8* __restrict__ wlo,
    const short8* __restrict__ wa, const short8* __restrict__ wb,
    const int* __restrict__ edges, int* __restrict__ cnt,
    unsigned short* __restrict__ xv, unsigned short* __restrict__ u_bf) {
    __shared__ __align__(16) unsigned short lds[4][16 * 72];
    if (blockIdx.x >= PROJ_BLOCKS) {
        const int e = (blockIdx.x - PROJ_BLOCKS) * 256 + threadIdx.x;
        if (e < N_EDGES) atomicAdd(&cnt[edges[e]], 1);
        return;
    }
    const int lane = threadIdx.x & 63;
    const int wv = threadIdx.x >> 6;
    const int c = lane & 15, q = lane >> 4;
    const int tile = blockIdx.x * 4 + wv;
    if (tile >= N_TILES) return;
    const int n0 = tile * 16;

    short8 Whi[4][2], Wlo[4][2], Wa[4][2], Wb[4][2];
    float bias[4];
#pragma unroll
    for (int nt = 0; nt < 4; ++nt) {
        bias[nt] = bl[nt * 16 + c];
#pragma unroll
        for (int ks = 0; ks < 2; ++ks) {
            const int idx = (nt * 2 + ks) * 64 + lane;
            Whi[nt][ks] = whi[idx]; Wlo[nt][ks] = wlo[idx];
            Wa[nt][ks] = wa[idx];   Wb[nt][ks] = wb[idx];
        }
    }

    // A (h rows), hi/lo bf16 split
    short8 Ahi[2], Alo[2];
#pragma unroll
    for (int ks = 0; ks < 2; ++ks) {
        const float* hp = h + (size_t)(n0 + c) * 64 + ks * 32 + q * 8;
        f32x4 p0 = *(const f32x4*)hp;
        f32x4 p1 = *(const f32x4*)(hp + 4);
        short8 hi8, lo8;
#pragma unroll
        for (int jj = 0; jj < 4; ++jj) {
            unsigned short hh = f2bf(p0[jj]);
            hi8[jj] = (short)hh; lo8[jj] = (short)f2bf(p0[jj] - bf2f(hh));
            unsigned short h2 = f2bf(p1[jj]);
            hi8[4 + jj] = (short)h2; lo8[4 + jj] = (short)f2bf(p1[jj] - bf2f(h2));
        }
        Ahi[ks] = hi8; Alo[ks] = lo8;
    }

    f32x4 xacc[4] = {{0,0,0,0},{0,0,0,0},{0,0,0,0},{0,0,0,0}};
#pragma unroll
    for (int ks = 0; ks < 2; ++ks)
#pragma unroll
        for (int nt = 0; nt < 4; ++nt) {
            xacc[nt] = __builtin_amdgcn_mfma_f32_16x16x32_bf16(Ahi[ks], Whi[nt][ks], xacc[nt], 0, 0, 0);
            xacc[nt] = __builtin_amdgcn_mfma_f32_16x16x32_bf16(Ahi[ks], Wlo[nt][ks], xacc[nt], 0, 0, 0);
            xacc[nt] = __builtin_amdgcn_mfma_f32_16x16x32_bf16(Alo[ks], Whi[nt][ks], xacc[nt], 0, 0, 0);
        }

    unsigned short* lw = lds[wv];
#pragma unroll
    for (int r = 0; r < 4; ++r) {
        const int node = n0 + q * 4 + r;
        unsigned short xb[4];
#pragma unroll
        for (int nt = 0; nt < 4; ++nt) {
            unsigned short v16 = f2bf(xacc[nt][r] + bias[nt]);
            xb[nt] = v16;
            lw[(q * 4 + r) * 72 + nt * 16 + c] = v16;
        }
        uint2 pk;
        pk.x = (unsigned)xb[0] | ((unsigned)xb[1] << 16);
        pk.y = (unsigned)xb[2] | ((unsigned)xb[3] << 16);
        *(uint2*)(xv + (size_t)node * 128 + c * 8) = pk;
    }

    // phase 2: x tile (row-major from LDS) -> u, v
    short8 Ax[2];
#pragma unroll
    for (int ks = 0; ks < 2; ++ks)
        Ax[ks] = *(const short8*)&lw[c * 72 + ks * 32 + q * 8];

    f32x4 uacc[4] = {{0,0,0,0},{0,0,0,0},{0,0,0,0},{0,0,0,0}};
    f32x4 vacc[4] = {{0,0,0,0},{0,0,0,0},{0,0,0,0},{0,0,0,0}};
#pragma unroll
    for (int ks = 0; ks < 2; ++ks)
#pragma unroll
        for (int nt = 0; nt < 4; ++nt) {
            uacc[nt] = __builtin_amdgcn_mfma_f32_16x16x32_bf16(Ax[ks], Wa[nt][ks], uacc[nt], 0, 0, 0);
            vacc[nt] = __builtin_amdgcn_mfma_f32_16x16x32_bf16(Ax[ks], Wb[nt][ks], vacc[nt], 0, 0, 0);
        }
#pragma unroll
    for (int r = 0; r < 4; ++r) {
        const int node = n0 + q * 4 + r;
        uint2 pu;
        pu.x = (unsigned)f2bf(uacc[0][r]) | ((unsigned)f2bf(uacc[1][r]) << 16);
        pu.y = (unsigned)f2bf(uacc[2][r]) | ((unsigned)f2bf(uacc[3][r]) << 16);
        *(uint2*)(u_bf + (size_t)node * 64 + c * 4) = pu;
        uint2 pk;
        pk.x = (unsigned)f2bf(vacc[0][r]) | ((unsigned)f2bf(vacc[1][r]) << 16);
        pk.y = (unsigned)f2bf(vacc[2][r]) | ((unsigned)f2bf(vacc[3][r]) << 16);
        *(uint2*)(xv + (size_t)node * 128 + c * 8 + 4) = pk;
    }
}

// ---------------------------------------------------------------------------
// Scan (padded to multiples of 4 per row): wave-shuffle version.
// ---------------------------------------------------------------------------
__global__ __launch_bounds__(1024) void scan_block(
    const int* __restrict__ cnt, int* __restrict__ start, int* __restrict__ bsum) {
    __shared__ int wsum[16];
    const int t = threadIdx.x;
    const int i = blockIdx.x * 1024 + t;
    const int lane = t & 63, w = t >> 6;
    const int v = (i < N_NODES) ? ((cnt[i] + 3) & ~3) : 0;
    int sc = v;
#pragma unroll
    for (int off = 1; off < 64; off <<= 1) {
        int u = __shfl_up(sc, off);
        sc = (lane >= off) ? sc + u : sc;
    }
    if (lane == 63) wsum[w] = sc;
    __syncthreads();
    if (w == 0) {
        int ws = (lane < 16) ? wsum[lane] : 0;
#pragma unroll
        for (int off = 1; off < 16; off <<= 1) {
            int u = __shfl_up(ws, off);
            ws = (lane >= off) ? ws + u : ws;
        }
        if (lane < 16) wsum[lane] = ws;  // inclusive wave sums
    }
    __syncthreads();
    const int wo = (w > 0) ? wsum[w - 1] : 0;
    if (i < N_NODES) start[i] = sc - v + wo;  // exclusive
    if (t == 1023) bsum[blockIdx.x] = wsum[15];
}

__global__ __launch_bounds__(1024) void scan_add(
    int* __restrict__ start, const int* __restrict__ bsum,
    int* __restrict__ cursor, const int* __restrict__ cnt) {
    __shared__ int partial[2];
    const int t = threadIdx.x;
    if (t < 128) {
        int v = (t < blockIdx.x) ? bsum[t] : 0;
#pragma unroll
        for (int off = 1; off < 64; off <<= 1) v += __shfl_xor(v, off);
        if ((t & 63) == 0) partial[t >> 6] = v;
    }
    __syncthreads();
    const int off = partial[0] + partial[1];
    const int i = blockIdx.x * 1024 + t;
    if (i < N_NODES) {
        const int s = start[i] + off;
        start[i] = s;
        cursor[i] = s;
        if (i == N_NODES - 1) start[N_NODES] = s + ((cnt[i] + 3) & ~3);
    }
}

// 8 B record per edge: {col, dist(bf16 lo) | emask*0.01(bf16 hi)}
__global__ __launch_bounds__(256) void scatter_kernel(
    const int* __restrict__ edges, const float* __restrict__ dist,
    const float* __restrict__ emask, int* __restrict__ cursor,
    uint2* __restrict__ recs) {
    const int e = blockIdx.x * 256 + threadIdx.x;
    if (e < N_EDGES) {
        const int r = edges[e];
        const int pos = atomicAdd(&cursor[r], 1);
        uint2 rc;
        rc.x = (unsigned)edges[N_EDGES + e];
        rc.y = (unsigned)f2bf(dist[e]) | ((unsigned)f2bf(emask[e] * NORM_INV) << 16);
        recs[pos] = rc;
    }
}

// ---------------------------------------------------------------------------
// agg: one wave per row. Segments are padded to x4 with zero records, so the
// inner loop is uniform: no clamps, no validity selects. Fused res+LN+SiLU.
// ---------------------------------------------------------------------------
__global__ __launch_bounds__(256, 8) void agg_ln_kernel(
    const int* __restrict__ start, const uint2* __restrict__ recs,
    const unsigned short* __restrict__ xv, const unsigned short* __restrict__ u_bf,
    const float* __restrict__ att_b1, const float* __restrict__ att_W1,
    const float* __restrict__ att_W2, const float* __restrict__ att_b2,
    const float* __restrict__ ln_g, const float* __restrict__ ln_b,
    float* __restrict__ out) {
    const int lane = threadIdx.x & 63;
    const int wv = threadIdx.x >> 6;
    const int j = lane & 15;
    const int s = lane >> 4;
    const int r = blockIdx.x * 4 + wv;

    float w2v[4], w1cv[4], base[4];
    const uint2 uu = *(const uint2*)(u_bf + (size_t)r * 64 + j * 4);
    const float u0 = __uint_as_float(uu.x << 16);
    const float u1 = __uint_as_float(uu.x & 0xffff0000u);
    const float u2 = __uint_as_float(uu.y << 16);
    const float u3 = __uint_as_float(uu.y & 0xffff0000u);
    const float uf[4] = {u0, u1, u2, u3};
#pragma unroll
    for (int k = 0; k < 4; ++k) {
        const int f = j + 16 * k;
        w2v[k] = att_W2[f];
        w1cv[k] = att_W1[f * 129 + 128];
        base[k] = uf[k] + att_b1[f];
    }
    const float b2 = att_b2[0];

    const int s0 = start[r];
    const int e1 = start[r + 1];
    const unsigned* xvu = (const unsigned*)xv;

    float a0 = 0.f, a1 = 0.f, a2 = 0.f, a3 = 0.f;
    if (e1 > s0) {
        uint2 recA = recs[s0 + s];
        uint4 xvA = *(const uint4*)(xvu + (size_t)recA.x * 64 + j * 4);
        uint2 recB = recs[s0 + 4 + s];
        for (int e = s0; e < e1; e += 4) {
            const uint2 recC = recs[e + 8 + s];
            const uint4 xvB = *(const uint4*)(xvu + (size_t)recB.x * 64 + j * 4);

            const float dist = __uint_as_float(recA.y << 16);
            const float emN = __uint_as_float(recA.y & 0xffff0000u);
            const float x0 = __uint_as_float(xvA.x << 16);
            const float x1 = __uint_as_float(xvA.x & 0xffff0000u);
            const float x2 = __uint_as_float(xvA.y << 16);
            const float x3 = __uint_as_float(xvA.y & 0xffff0000u);
            const float v0 = __uint_as_float(xvA.z << 16);
            const float v1 = __uint_as_float(xvA.z & 0xffff0000u);
            const float v2 = __uint_as_float(xvA.w << 16);
            const float v3 = __uint_as_float(xvA.w & 0xffff0000u);
            float pv = 0.f, pre, t;
            pre = fmaf(dist, w1cv[0], base[0]) + v0; t = pre / (1.f + __expf(-pre)); pv = fmaf(t, w2v[0], pv);
            pre = fmaf(dist, w1cv[1], base[1]) + v1; t = pre / (1.f + __expf(-pre)); pv = fmaf(t, w2v[1], pv);
            pre = fmaf(dist, w1cv[2], base[2]) + v2; t = pre / (1.f + __expf(-pre)); pv = fmaf(t, w2v[2], pv);
            pre = fmaf(dist, w1cv[3], base[3]) + v3; t = pre / (1.f + __expf(-pre)); pv = fmaf(t, w2v[3], pv);
            pv += __shfl_xor(pv, 1); pv += __shfl_xor(pv, 2);
            pv += __shfl_xor(pv, 4); pv += __shfl_xor(pv, 8);
            const float att = emN / (1.f + __expf(-(pv + b2)));
            a0 = fmaf(att, x0, a0); a1 = fmaf(att, x1, a1);
            a2 = fmaf(att, x2, a2); a3 = fmaf(att, x3, a3);
            recA = recB; xvA = xvB; recB = recC;
        }
    }
    a0 += __shfl_xor(a0, 16); a0 += __shfl_xor(a0, 32);
    a1 += __shfl_xor(a1, 16); a1 += __shfl_xor(a1, 32);
    a2 += __shfl_xor(a2, 16); a2 += __shfl_xor(a2, 32);
    a3 += __shfl_xor(a3, 16); a3 += __shfl_xor(a3, 32);

    const uint2 xr = *(const uint2*)(xvu + (size_t)r * 64 + j * 4);
    const float o0 = __uint_as_float(xr.x << 16) + a0;
    const float o1 = __uint_as_float(xr.x & 0xffff0000u) + a1;
    const float o2 = __uint_as_float(xr.y << 16) + a2;
    const float o3 = __uint_as_float(xr.y & 0xffff0000u) + a3;

    float ssum = o0 + o1 + o2 + o3;
    ssum += __shfl_xor(ssum, 1); ssum += __shfl_xor(ssum, 2);
    ssum += __shfl_xor(ssum, 4); ssum += __shfl_xor(ssum, 8);
    const float mu = ssum * (1.f / 64.f);
    const float d0 = o0 - mu, d1 = o1 - mu, d2 = o2 - mu, d3 = o3 - mu;
    float vs = d0 * d0 + d1 * d1 + d2 * d2 + d3 * d3;
    vs += __shfl_xor(vs, 1); vs += __shfl_xor(vs, 2);
    vs += __shfl_xor(vs, 4); vs += __shfl_xor(vs, 8);
    const float rstd = rsqrtf(vs * (1.f / 64.f) + LN_EPS);

    const int f = j + 16 * s;
    const float dk = (s == 0) ? d0 : (s == 1) ? d1 : (s == 2) ? d2 : d3;
    const float y = fmaf(dk * rstd, ln_g[f], ln_b[f]);
    out[(size_t)r * 64 + lane] = y / (1.f + __expf(-y));
}

extern "C" void kernel_launch(void* const* d_in, const int* in_sizes, int n_in,
                              void* d_out, int out_size, void* d_ws, size_t ws_size,
                              hipStream_t stream) {
    const float* h      = (const float*)d_in[0];
    const float* dist   = (const float*)d_in[1];
    const int*   edges  = (const int*)d_in[2];
    const float* emask  = (const float*)d_in[4];
    const float* W_lin  = (const float*)d_in[5];
    const float* b_lin  = (const float*)d_in[6];
    const float* att_W1 = (const float*)d_in[7];
    const float* att_b1 = (const float*)d_in[8];
    const float* att_W2 = (const float*)d_in[9];
    const float* att_b2 = (const float*)d_in[10];
    const float* ln_g   = (const float*)d_in[11];
    const float* ln_b   = (const float*)d_in[12];
    float* out = (float*)d_out;

    char* ws = (char*)d_ws;
    unsigned short* xv   = (unsigned short*)ws;                 // 25.6 MB
    unsigned short* u_bf = (unsigned short*)(ws + 25600000);    // 12.8 MB
    uint2* recs   = (uint2*)(ws + 38400000);                    // 11.2 MB (padded)
    int* cnt      = (int*)(ws + 49600640);
    int* start    = (int*)(ws + 50000640);
    int* cursor   = (int*)(ws + 50400768);
    int* bsum     = (int*)(ws + 50800768);
    short8* whi   = (short8*)(ws + 50801280);
    short8* wlo   = (short8*)(ws + 50809472);
    short8* wa    = (short8*)(ws + 50817664);
    short8* wb    = (short8*)(ws + 50825856);

    const int NB = (N_NODES + 1023) / 1024;  // 98

    hipMemsetAsync(cnt, 0, N_NODES * sizeof(int), stream);
    hipMemsetAsync(recs, 0, 11200640, stream);  // 1,400,080 recs, zero = pad
    prep_frags<<<1, 256, 0, stream>>>(W_lin, att_W1, whi, wlo, wa, wb);
    proj_hist<<<PROJ_BLOCKS + HIST_BLOCKS, 256, 0, stream>>>(
        h, b_lin, whi, wlo, wa, wb, edges, cnt, xv, u_bf);
    scan_block<<<NB, 1024, 0, stream>>>(cnt, start, bsum);
    scan_add<<<NB, 1024, 0, stream>>>(start, bsum, cursor, cnt);
    scatter_kernel<<<HIST_BLOCKS, 256, 0, stream>>>(edges, dist, emask, cursor, recs);
    agg_ln_kernel<<<N_NODES / 4, 256, 0, stream>>>(start, recs, xv, u_bf,
                                                   att_b1, att_W1, att_W2, att_b2,
                                                   ln_g, ln_b, out);
}

// Round 5
// 237.917 us; speedup vs baseline: 1.7748x; 1.2123x over previous
//
#include <hip/hip_runtime.h>
#include <hip/hip_bf16.h>

#define N_NODES 100000
#define N_EDGES 1000000
#define DIM 64
#define NORM_INV 0.01f
#define LN_EPS 1e-5f
#define N_TILES 6250          // N_NODES/16
#define PROJ_BLOCKS 1563      // ceil(6250/4)
#define N_BUCKETS 782         // ceil(100000/128), 128 rows per bucket
#define HISTB 489             // ceil(1e6/2048)
#define L2E 1.4426950408889634f
#define LN2 0.6931471805599453f

typedef __attribute__((ext_vector_type(8))) short short8;
typedef __attribute__((ext_vector_type(4))) float f32x4;

__device__ __forceinline__ unsigned short f2bf(float f) {
    union { float f; unsigned u; } x; x.f = f;
    unsigned r = x.u + 0x7FFFu + ((x.u >> 16) & 1u);
    return (unsigned short)(r >> 16);
}
__device__ __forceinline__ float bf2f(unsigned short s) {
    union { unsigned u; float f; } x; x.u = ((unsigned)s) << 16; return x.f;
}

// ---------------------------------------------------------------------------
// P0: precompute MFMA weight fragments + per-feature epilogue table.
// tab[f] = {w2[f]*ln2, w1c[f]*log2e, b1[f]*log2e, 0}
// ---------------------------------------------------------------------------
__global__ __launch_bounds__(256) void prep_frags(
    const float* __restrict__ W, const float* __restrict__ att_W1,
    const float* __restrict__ att_b1, const float* __restrict__ att_W2,
    short8* __restrict__ whi, short8* __restrict__ wlo,
    short8* __restrict__ wa, short8* __restrict__ wb,
    float4* __restrict__ tab) {
    const int l = threadIdx.x & 63;
    const int nt = threadIdx.x >> 6;
    const int c = l & 15, q = l >> 4;
    const int n = nt * 16 + c;
#pragma unroll
    for (int ks = 0; ks < 2; ++ks) {
        const int k0 = ks * 32 + q * 8;
        short8 hi8, lo8, a8, b8;
#pragma unroll
        for (int jj = 0; jj < 8; ++jj) {
            float w = W[n * 64 + k0 + jj];
            unsigned short hh = f2bf(w);
            hi8[jj] = (short)hh;
            lo8[jj] = (short)f2bf(w - bf2f(hh));
            a8[jj] = (short)f2bf(att_W1[n * 129 + k0 + jj]);
            b8[jj] = (short)f2bf(att_W1[n * 129 + 64 + k0 + jj]);
        }
        const int idx = (nt * 2 + ks) * 64 + l;
        whi[idx] = hi8; wlo[idx] = lo8; wa[idx] = a8; wb[idx] = b8;
    }
    if (threadIdx.x < 64) {
        const int f = threadIdx.x;
        tab[f] = make_float4(att_W2[f] * LN2, att_W1[f * 129 + 128] * L2E,
                             att_b1[f] * L2E, 0.f);
    }
}

// ---------------------------------------------------------------------------
// P1 fat kernel. blocks [0,PROJ_BLOCKS): MFMA projection, 1 tile/wave.
//   x = h@W^T + b (hi/lo bf16 split), u = x@W1a^T * log2e, v = x@W1b^T * log2e
// blocks [PROJ_BLOCKS, +HISTB): bucket histogram (LDS-staged, 1 atomic/bucket).
// ---------------------------------------------------------------------------
__global__ __launch_bounds__(256) void proj_hist(
    const float* __restrict__ h, const float* __restrict__ bl,
    const short8* __restrict__ whi, const short8* __restrict__ wlo,
    const short8* __restrict__ wa, const short8* __restrict__ wb,
    const int* __restrict__ edges, int* __restrict__ bucketCnt,
    unsigned short* __restrict__ xv, unsigned short* __restrict__ u_bf) {
    if (blockIdx.x >= PROJ_BLOCKS) {
        __shared__ int lh[N_BUCKETS];
        const int tid = threadIdx.x;
        for (int i = tid; i < N_BUCKETS; i += 256) lh[i] = 0;
        __syncthreads();
        const int e0 = (blockIdx.x - PROJ_BLOCKS) * 2048;
#pragma unroll
        for (int i = 0; i < 8; ++i) {
            const int e = e0 + tid * 8 + i;
            if (e < N_EDGES) atomicAdd(&lh[edges[e] >> 7], 1);
        }
        __syncthreads();
        for (int b = tid; b < N_BUCKETS; b += 256)
            if (lh[b]) atomicAdd(&bucketCnt[b], lh[b]);
        return;
    }
    __shared__ __align__(16) unsigned short lds[4][16 * 72];
    const int lane = threadIdx.x & 63;
    const int wv = threadIdx.x >> 6;
    const int c = lane & 15, q = lane >> 4;
    const int tile = blockIdx.x * 4 + wv;
    if (tile >= N_TILES) return;
    const int n0 = tile * 16;

    short8 Whi[4][2], Wlo[4][2], Wa[4][2], Wb[4][2];
    float bias[4];
#pragma unroll
    for (int nt = 0; nt < 4; ++nt) {
        bias[nt] = bl[nt * 16 + c];
#pragma unroll
        for (int ks = 0; ks < 2; ++ks) {
            const int idx = (nt * 2 + ks) * 64 + lane;
            Whi[nt][ks] = whi[idx]; Wlo[nt][ks] = wlo[idx];
            Wa[nt][ks] = wa[idx];   Wb[nt][ks] = wb[idx];
        }
    }

    short8 Ahi[2], Alo[2];
#pragma unroll
    for (int ks = 0; ks < 2; ++ks) {
        const float* hp = h + (size_t)(n0 + c) * 64 + ks * 32 + q * 8;
        f32x4 p0 = *(const f32x4*)hp;
        f32x4 p1 = *(const f32x4*)(hp + 4);
        short8 hi8, lo8;
#pragma unroll
        for (int jj = 0; jj < 4; ++jj) {
            unsigned short hh = f2bf(p0[jj]);
            hi8[jj] = (short)hh; lo8[jj] = (short)f2bf(p0[jj] - bf2f(hh));
            unsigned short h2 = f2bf(p1[jj]);
            hi8[4 + jj] = (short)h2; lo8[4 + jj] = (short)f2bf(p1[jj] - bf2f(h2));
        }
        Ahi[ks] = hi8; Alo[ks] = lo8;
    }

    f32x4 xacc[4] = {{0,0,0,0},{0,0,0,0},{0,0,0,0},{0,0,0,0}};
#pragma unroll
    for (int ks = 0; ks < 2; ++ks)
#pragma unroll
        for (int nt = 0; nt < 4; ++nt) {
            xacc[nt] = __builtin_amdgcn_mfma_f32_16x16x32_bf16(Ahi[ks], Whi[nt][ks], xacc[nt], 0, 0, 0);
            xacc[nt] = __builtin_amdgcn_mfma_f32_16x16x32_bf16(Ahi[ks], Wlo[nt][ks], xacc[nt], 0, 0, 0);
            xacc[nt] = __builtin_amdgcn_mfma_f32_16x16x32_bf16(Alo[ks], Whi[nt][ks], xacc[nt], 0, 0, 0);
        }

    unsigned short* lw = lds[wv];
#pragma unroll
    for (int r = 0; r < 4; ++r) {
        const int node = n0 + q * 4 + r;
        unsigned short xb[4];
#pragma unroll
        for (int nt = 0; nt < 4; ++nt) {
            unsigned short v16 = f2bf(xacc[nt][r] + bias[nt]);
            xb[nt] = v16;
            lw[(q * 4 + r) * 72 + nt * 16 + c] = v16;
        }
        uint2 pk;
        pk.x = (unsigned)xb[0] | ((unsigned)xb[1] << 16);
        pk.y = (unsigned)xb[2] | ((unsigned)xb[3] << 16);
        *(uint2*)(xv + (size_t)node * 128 + c * 8) = pk;
    }

    short8 Ax[2];
#pragma unroll
    for (int ks = 0; ks < 2; ++ks)
        Ax[ks] = *(const short8*)&lw[c * 72 + ks * 32 + q * 8];

    f32x4 uacc[4] = {{0,0,0,0},{0,0,0,0},{0,0,0,0},{0,0,0,0}};
    f32x4 vacc[4] = {{0,0,0,0},{0,0,0,0},{0,0,0,0},{0,0,0,0}};
#pragma unroll
    for (int ks = 0; ks < 2; ++ks)
#pragma unroll
        for (int nt = 0; nt < 4; ++nt) {
            uacc[nt] = __builtin_amdgcn_mfma_f32_16x16x32_bf16(Ax[ks], Wa[nt][ks], uacc[nt], 0, 0, 0);
            vacc[nt] = __builtin_amdgcn_mfma_f32_16x16x32_bf16(Ax[ks], Wb[nt][ks], vacc[nt], 0, 0, 0);
        }
#pragma unroll
    for (int r = 0; r < 4; ++r) {
        const int node = n0 + q * 4 + r;
        uint2 pu;
        pu.x = (unsigned)f2bf(uacc[0][r] * L2E) | ((unsigned)f2bf(uacc[1][r] * L2E) << 16);
        pu.y = (unsigned)f2bf(uacc[2][r] * L2E) | ((unsigned)f2bf(uacc[3][r] * L2E) << 16);
        *(uint2*)(u_bf + (size_t)node * 64 + c * 4) = pu;
        uint2 pk;
        pk.x = (unsigned)f2bf(vacc[0][r] * L2E) | ((unsigned)f2bf(vacc[1][r] * L2E) << 16);
        pk.y = (unsigned)f2bf(vacc[2][r] * L2E) | ((unsigned)f2bf(vacc[3][r] * L2E) << 16);
        *(uint2*)(xv + (size_t)node * 128 + c * 8 + 4) = pk;
    }
}

// ---------------------------------------------------------------------------
// scanA: exclusive scan of bucketCnt -> baseA (staging bases) + cursA.
// ---------------------------------------------------------------------------
__global__ __launch_bounds__(1024) void scanA(
    const int* __restrict__ bucketCnt, int* __restrict__ baseA,
    int* __restrict__ cursA) {
    __shared__ int wsum[16];
    const int t = threadIdx.x, lane = t & 63, w = t >> 6;
    const int v = (t < N_BUCKETS) ? bucketCnt[t] : 0;
    int sc = v;
#pragma unroll
    for (int off = 1; off < 64; off <<= 1) {
        int u = __shfl_up(sc, off);
        if (lane >= off) sc += u;
    }
    if (lane == 63) wsum[w] = sc;
    __syncthreads();
    if (w == 0) {
        int x = (lane < 16) ? wsum[lane] : 0;
#pragma unroll
        for (int off = 1; off < 16; off <<= 1) {
            int u = __shfl_up(x, off);
            if (lane >= off) x += u;
        }
        if (lane < 16) wsum[lane] = x;
    }
    __syncthreads();
    const int excl = sc - v + ((w > 0) ? wsum[w - 1] : 0);
    if (t < N_BUCKETS) { baseA[t] = excl; cursA[t] = excl; }
    if (t == N_BUCKETS - 1) baseA[N_BUCKETS] = excl + v;
}

// ---------------------------------------------------------------------------
// scatterA: stage edges into bucket regions. 2048 edges/block, LDS-ranked so
// writes to each bucket region are block-bursts. srec = {col, dist|em packed},
// lrowS = row & 127 (1 B).
// ---------------------------------------------------------------------------
__global__ __launch_bounds__(256) void scatterA(
    const int* __restrict__ edges, const float* __restrict__ dist,
    const float* __restrict__ emask, int* __restrict__ cursA,
    uint2* __restrict__ srec, unsigned char* __restrict__ lrowS) {
    __shared__ int lh[N_BUCKETS];
    __shared__ int lb[N_BUCKETS];
    const int tid = threadIdx.x;
    for (int i = tid; i < N_BUCKETS; i += 256) lh[i] = 0;
    __syncthreads();

    const int e0 = blockIdx.x * 2048 + tid * 8;
    int row[8], col[8];
    unsigned de[8];
#pragma unroll
    for (int i = 0; i < 8; ++i) {
        const int e = e0 + i;
        if (e < N_EDGES) {
            row[i] = edges[e];
            col[i] = edges[N_EDGES + e];
            de[i] = (unsigned)f2bf(dist[e]) | ((unsigned)f2bf(emask[e] * NORM_INV) << 16);
            atomicAdd(&lh[row[i] >> 7], 1);
        } else {
            row[i] = -1;
        }
    }
    __syncthreads();
    for (int b = tid; b < N_BUCKETS; b += 256) {
        const int c = lh[b];
        lb[b] = c ? atomicAdd(&cursA[b], c) : 0;
    }
    __syncthreads();
    for (int i = tid; i < N_BUCKETS; i += 256) lh[i] = 0;
    __syncthreads();
#pragma unroll
    for (int i = 0; i < 8; ++i) {
        if (row[i] >= 0) {
            const int bk = row[i] >> 7;
            const int rk = atomicAdd(&lh[bk], 1);
            const int pos = lb[bk] + rk;
            uint2 rc; rc.x = (unsigned)col[i]; rc.y = de[i];
            srec[pos] = rc;
            lrowS[pos] = (unsigned char)(row[i] & 127);
        }
    }
}

// ---------------------------------------------------------------------------
// B1: per bucket, padded (x4) total -> pbt[b]
// ---------------------------------------------------------------------------
__global__ __launch_bounds__(256) void bucketB1(
    const int* __restrict__ baseA, const unsigned char* __restrict__ lrowS,
    int* __restrict__ pbt) {
    __shared__ int hist[128];
    __shared__ int tt[4];
    const int tid = threadIdx.x;
    const int b = blockIdx.x;
    if (tid < 128) hist[tid] = 0;
    __syncthreads();
    const int s0 = baseA[b], s1 = baseA[b + 1];
    for (int e = s0 + tid; e < s1; e += 256) atomicAdd(&hist[lrowS[e]], 1);
    __syncthreads();
    int p = (tid < 128) ? ((hist[tid] + 3) & ~3) : 0;
#pragma unroll
    for (int off = 1; off < 64; off <<= 1) p += __shfl_xor(p, off);
    if ((tid & 63) == 0) tt[tid >> 6] = p;
    __syncthreads();
    if (tid == 0) pbt[b] = tt[0] + tt[1];
}

// ---------------------------------------------------------------------------
// scanB: scan pbt -> baseB (final bases); start[N]=total; zero 16 slack recs.
// ---------------------------------------------------------------------------
__global__ __launch_bounds__(1024) void scanB(
    const int* __restrict__ pbt, int* __restrict__ baseB,
    int* __restrict__ start, uint2* __restrict__ recs) {
    __shared__ int wsum[16];
    const int t = threadIdx.x, lane = t & 63, w = t >> 6;
    const int v = (t < N_BUCKETS) ? pbt[t] : 0;
    int sc = v;
#pragma unroll
    for (int off = 1; off < 64; off <<= 1) {
        int u = __shfl_up(sc, off);
        if (lane >= off) sc += u;
    }
    if (lane == 63) wsum[w] = sc;
    __syncthreads();
    if (w == 0) {
        int x = (lane < 16) ? wsum[lane] : 0;
#pragma unroll
        for (int off = 1; off < 16; off <<= 1) {
            int u = __shfl_up(x, off);
            if (lane >= off) x += u;
        }
        if (lane < 16) wsum[lane] = x;
    }
    __syncthreads();
    const int excl = sc - v + ((w > 0) ? wsum[w - 1] : 0);
    if (t < N_BUCKETS) baseB[t] = excl;
    if (t == N_BUCKETS - 1) {
        const int tot = excl + v;
        baseB[N_BUCKETS] = tot;
        start[N_NODES] = tot;
        uint2 z; z.x = 0; z.y = 0;
        for (int i = 0; i < 16; ++i) recs[tot + i] = z;
    }
}

// ---------------------------------------------------------------------------
// B2: per bucket, LDS counting sort by local row -> final recs (coalesced
// block-local region), row starts, zero pad slots.
// ---------------------------------------------------------------------------
__global__ __launch_bounds__(256) void bucketB2(
    const int* __restrict__ baseA, const int* __restrict__ baseB,
    const unsigned char* __restrict__ lrowS, const uint2* __restrict__ srec,
    uint2* __restrict__ recs, int* __restrict__ start) {
    __shared__ int hist[128];
    __shared__ int cur[128];
    __shared__ int wtot;
    const int tid = threadIdx.x, lane = tid & 63;
    const int b = blockIdx.x;
    if (tid < 128) hist[tid] = 0;
    __syncthreads();
    const int s0 = baseA[b], s1 = baseA[b + 1];
    for (int e = s0 + tid; e < s1; e += 256) atomicAdd(&hist[lrowS[e]], 1);
    __syncthreads();
    int c = 0, p = 0, sc = 0;
    if (tid < 128) {
        c = hist[tid];
        p = (c + 3) & ~3;
        sc = p;
#pragma unroll
        for (int off = 1; off < 64; off <<= 1) {
            int u = __shfl_up(sc, off);
            if (lane >= off) sc += u;
        }
        if (tid == 63) wtot = sc;
    }
    __syncthreads();
    if (tid < 128) {
        if (tid >= 64) sc += wtot;
        const int excl = baseB[b] + sc - p;
        cur[tid] = excl;
        const int grow = b * 128 + tid;
        if (grow < N_NODES) start[grow] = excl;
        uint2 z; z.x = 0; z.y = 0;
        for (int i = c; i < p; ++i) recs[excl + i] = z;
    }
    __syncthreads();
    for (int e = s0 + tid; e < s1; e += 256) {
        const int lr = lrowS[e];
        const uint2 rc = srec[e];
        const int pos = atomicAdd(&cur[lr], 1);
        recs[pos] = rc;
    }
}

// ---------------------------------------------------------------------------
// agg: one wave/row, 4 edge-slots x 16 feature-lanes. Division-free silu /
// sigmoid via exp2+rcp with log2e folded into stored u,v and tab.
// ---------------------------------------------------------------------------
__global__ __launch_bounds__(256, 8) void agg_ln_kernel(
    const int* __restrict__ start, const uint2* __restrict__ recs,
    const unsigned short* __restrict__ xv, const unsigned short* __restrict__ u_bf,
    const float4* __restrict__ tab, const float* __restrict__ att_b2,
    const float* __restrict__ ln_g, const float* __restrict__ ln_b,
    float* __restrict__ out) {
    const int lane = threadIdx.x & 63;
    const int wv = threadIdx.x >> 6;
    const int j = lane & 15;
    const int s = lane >> 4;
    const int r = blockIdx.x * 4 + wv;

    const float4 t0 = tab[j], t1 = tab[j + 16], t2 = tab[j + 32], t3 = tab[j + 48];
    const uint2 uu = *(const uint2*)(u_bf + (size_t)r * 64 + j * 4);
    const float base0 = __uint_as_float(uu.x << 16) + t0.z;
    const float base1 = __uint_as_float(uu.x & 0xffff0000u) + t1.z;
    const float base2 = __uint_as_float(uu.y << 16) + t2.z;
    const float base3 = __uint_as_float(uu.y & 0xffff0000u) + t3.z;
    const float b2L = att_b2[0] * L2E;

    const int s0 = start[r];
    const int e1 = start[r + 1];
    const unsigned* xvu = (const unsigned*)xv;

    float a0 = 0.f, a1 = 0.f, a2 = 0.f, a3 = 0.f;
    if (e1 > s0) {
        uint2 recA = recs[s0 + s];
        uint4 xvA = *(const uint4*)(xvu + (size_t)recA.x * 64 + j * 4);
        uint2 recB = recs[s0 + 4 + s];
        for (int e = s0; e < e1; e += 4) {
            const uint2 recC = recs[e + 8 + s];
            const uint4 xvB = *(const uint4*)(xvu + (size_t)recB.x * 64 + j * 4);

            const float dist = __uint_as_float(recA.y << 16);
            const float emN = __uint_as_float(recA.y & 0xffff0000u);
            const float x0 = __uint_as_float(xvA.x << 16);
            const float x1 = __uint_as_float(xvA.x & 0xffff0000u);
            const float x2 = __uint_as_float(xvA.y << 16);
            const float x3 = __uint_as_float(xvA.y & 0xffff0000u);
            const float v0 = __uint_as_float(xvA.z << 16);
            const float v1 = __uint_as_float(xvA.z & 0xffff0000u);
            const float v2 = __uint_as_float(xvA.w << 16);
            const float v3 = __uint_as_float(xvA.w & 0xffff0000u);
            float pv = 0.f, pre, sg;
            pre = fmaf(dist, t0.y, base0) + v0;
            sg = __builtin_amdgcn_rcpf(1.f + __builtin_amdgcn_exp2f(-pre));
            pv = fmaf(pre * sg, t0.x, pv);
            pre = fmaf(dist, t1.y, base1) + v1;
            sg = __builtin_amdgcn_rcpf(1.f + __builtin_amdgcn_exp2f(-pre));
            pv = fmaf(pre * sg, t1.x, pv);
            pre = fmaf(dist, t2.y, base2) + v2;
            sg = __builtin_amdgcn_rcpf(1.f + __builtin_amdgcn_exp2f(-pre));
            pv = fmaf(pre * sg, t2.x, pv);
            pre = fmaf(dist, t3.y, base3) + v3;
            sg = __builtin_amdgcn_rcpf(1.f + __builtin_amdgcn_exp2f(-pre));
            pv = fmaf(pre * sg, t3.x, pv);
            pv += __shfl_xor(pv, 1); pv += __shfl_xor(pv, 2);
            pv += __shfl_xor(pv, 4); pv += __shfl_xor(pv, 8);
            const float sp = fmaf(pv, L2E, b2L);
            const float att =
                emN * __builtin_amdgcn_rcpf(1.f + __builtin_amdgcn_exp2f(-sp));
            a0 = fmaf(att, x0, a0); a1 = fmaf(att, x1, a1);
            a2 = fmaf(att, x2, a2); a3 = fmaf(att, x3, a3);
            recA = recB; xvA = xvB; recB = recC;
        }
    }
    a0 += __shfl_xor(a0, 16); a0 += __shfl_xor(a0, 32);
    a1 += __shfl_xor(a1, 16); a1 += __shfl_xor(a1, 32);
    a2 += __shfl_xor(a2, 16); a2 += __shfl_xor(a2, 32);
    a3 += __shfl_xor(a3, 16); a3 += __shfl_xor(a3, 32);

    const uint2 xr = *(const uint2*)(xvu + (size_t)r * 64 + j * 4);
    const float o0 = __uint_as_float(xr.x << 16) + a0;
    const float o1 = __uint_as_float(xr.x & 0xffff0000u) + a1;
    const float o2 = __uint_as_float(xr.y << 16) + a2;
    const float o3 = __uint_as_float(xr.y & 0xffff0000u) + a3;

    float ssum = o0 + o1 + o2 + o3;
    ssum += __shfl_xor(ssum, 1); ssum += __shfl_xor(ssum, 2);
    ssum += __shfl_xor(ssum, 4); ssum += __shfl_xor(ssum, 8);
    const float mu = ssum * (1.f / 64.f);
    const float d0 = o0 - mu, d1 = o1 - mu, d2 = o2 - mu, d3 = o3 - mu;
    float vs = d0 * d0 + d1 * d1 + d2 * d2 + d3 * d3;
    vs += __shfl_xor(vs, 1); vs += __shfl_xor(vs, 2);
    vs += __shfl_xor(vs, 4); vs += __shfl_xor(vs, 8);
    const float rstd = rsqrtf(vs * (1.f / 64.f) + LN_EPS);

    const int f = j + 16 * s;
    const float dk = (s == 0) ? d0 : (s == 1) ? d1 : (s == 2) ? d2 : d3;
    const float y = fmaf(dk * rstd, ln_g[f], ln_b[f]);
    out[(size_t)r * 64 + lane] =
        y * __builtin_amdgcn_rcpf(1.f + __builtin_amdgcn_exp2f(-y * L2E));
}

extern "C" void kernel_launch(void* const* d_in, const int* in_sizes, int n_in,
                              void* d_out, int out_size, void* d_ws, size_t ws_size,
                              hipStream_t stream) {
    const float* h      = (const float*)d_in[0];
    const float* dist   = (const float*)d_in[1];
    const int*   edges  = (const int*)d_in[2];
    const float* emask  = (const float*)d_in[4];
    const float* W_lin  = (const float*)d_in[5];
    const float* b_lin  = (const float*)d_in[6];
    const float* att_W1 = (const float*)d_in[7];
    const float* att_b1 = (const float*)d_in[8];
    const float* att_W2 = (const float*)d_in[9];
    const float* att_b2 = (const float*)d_in[10];
    const float* ln_g   = (const float*)d_in[11];
    const float* ln_b   = (const float*)d_in[12];
    float* out = (float*)d_out;

    char* ws = (char*)d_ws;
    unsigned short* xv   = (unsigned short*)ws;                  // 25.6 MB
    unsigned short* u_bf = (unsigned short*)(ws + 25600000);     // 12.8 MB
    uint2* srec          = (uint2*)(ws + 38400000);              // 8 MB
    uint2* recs          = (uint2*)(ws + 46400000);              // 10.4 MB
    unsigned char* lrowS = (unsigned char*)(ws + 56800128);      // 1 MB
    int* start           = (int*)(ws + 57800192);                // 400 KB
    int* bucketCnt       = (int*)(ws + 58200576);
    int* baseA           = (int*)(ws + 58204672);
    int* cursA           = (int*)(ws + 58208768);
    int* pbt             = (int*)(ws + 58212864);
    int* baseB           = (int*)(ws + 58216960);
    float4* tab          = (float4*)(ws + 58221056);
    short8* whi          = (short8*)(ws + 58222080);
    short8* wlo          = (short8*)(ws + 58230272);
    short8* wa           = (short8*)(ws + 58238464);
    short8* wb           = (short8*)(ws + 58246656);

    hipMemsetAsync(bucketCnt, 0, N_BUCKETS * sizeof(int), stream);
    prep_frags<<<1, 256, 0, stream>>>(W_lin, att_W1, att_b1, att_W2,
                                      whi, wlo, wa, wb, tab);
    proj_hist<<<PROJ_BLOCKS + HISTB, 256, 0, stream>>>(
        h, b_lin, whi, wlo, wa, wb, edges, bucketCnt, xv, u_bf);
    scanA<<<1, 1024, 0, stream>>>(bucketCnt, baseA, cursA);
    scatterA<<<HISTB, 256, 0, stream>>>(edges, dist, emask, cursA, srec, lrowS);
    bucketB1<<<N_BUCKETS, 256, 0, stream>>>(baseA, lrowS, pbt);
    scanB<<<1, 1024, 0, stream>>>(pbt, baseB, start, recs);
    bucketB2<<<N_BUCKETS, 256, 0, stream>>>(baseA, baseB, lrowS, srec, recs, start);
    agg_ln_kernel<<<N_NODES / 4, 256, 0, stream>>>(start, recs, xv, u_bf,
                                                   tab, att_b2, ln_g, ln_b, out);
}